// Round 5
// baseline (410.285 us; speedup 1.0000x reference)
//
#include <hip/hip_runtime.h>
#include <hip/hip_fp16.h>

#define B_SZ  256
#define IC    1152
#define ID    8
#define OC    10
#define ODIM  16
#define ROWH  160      // halves per (b,i) row of u_hat
#define CH    20       // uint4 (8-half) chunks per row
#define BC    16       // b per K1 block
#define ICH   32       // i per K1 block

// ---------------------------------------------------------------------------
// K1: u_hat = W u (fp16, [b][i][160]) + s0-partials (s0[b][od] = sum_i u_hat).
// grid = (1152/ICH)*(256/BC) = 36*16 = 576 blocks, 256 threads = 8 halves.
// Half h owns i-locals {h, h+8, h+16, h+24}; lane c<20 owns od-chunk [8c,8c+8).
// W lane-block (16 float4 = 64 VGPR) loaded once per i, reused for 16 b.
// s0 partial accumulated in LDS via ds_add_f32 (2 copies: wave-half parity),
// flushed once per block with global atomicAdd.
// ---------------------------------------------------------------------------
__global__ __launch_bounds__(256) void uhat_s0_kernel(
    const float* __restrict__ u, const float* __restrict__ W,
    uint4* __restrict__ uhat, float* __restrict__ s0g)
{
    const int bx     = blockIdx.x;
    const int ic_blk = bx >> 4;      // 0..35
    const int bc_blk = bx & 15;      // 0..15
    const int i0 = ic_blk * ICH;
    const int b0 = bc_blk * BC;

    const int t = threadIdx.x;
    const int h = t >> 5;            // half 0..7
    const int c = t & 31;
    const bool act = (c < CH);
    const int cc = act ? c : (CH - 1);
    const int par = h & 1;           // same-wave halves get separate s0 copies

    __shared__ float4 ul[BC * ICH * 2];       // 16 KB: u[bb][ii] as 2 float4
    __shared__ float  s0l[2][BC][ROWH];       // 20 KB

    for (int idx = t; idx < 2 * BC * ROWH; idx += 256) ((float*)s0l)[idx] = 0.f;

    const float4* uf4 = (const float4*)u;
    #pragma unroll
    for (int r = 0; r < 4; ++r) {
        int idx = t + 256 * r;
        int bb = idx >> 6, rem = idx & 63, ii = rem >> 1, part = rem & 1;
        ul[idx] = uf4[((size_t)(b0 + bb) * IC + (i0 + ii)) * 2 + part];
    }
    __syncthreads();

    const float4* wf4 = (const float4*)W;

    for (int t4 = 0; t4 < 4; ++t4) {
        const int ii = h + 8 * t4;
        const int i  = i0 + ii;

        float4 Wr[16];
        {
            const float4* wsrc = wf4 + (size_t)i * 320 + cc * 16;
            #pragma unroll
            for (int m = 0; m < 16; ++m) Wr[m] = wsrc[m];
        }

        #pragma unroll 2
        for (int bb = 0; bb < BC; ++bb) {
            float4 u0 = ul[(bb * ICH + ii) * 2];
            float4 u1 = ul[(bb * ICH + ii) * 2 + 1];
            float o[8];
            #pragma unroll
            for (int j = 0; j < 8; ++j) {
                float4 wa = Wr[2 * j], wb = Wr[2 * j + 1];
                o[j] = wa.x * u0.x + wa.y * u0.y + wa.z * u0.z + wa.w * u0.w
                     + wb.x * u1.x + wb.y * u1.y + wb.z * u1.z + wb.w * u1.w;
            }
            if (act) {
                union { __half2 h2[4]; uint4 q; } pk;
                pk.h2[0] = __floats2half2_rn(o[0], o[1]);
                pk.h2[1] = __floats2half2_rn(o[2], o[3]);
                pk.h2[2] = __floats2half2_rn(o[4], o[5]);
                pk.h2[3] = __floats2half2_rn(o[6], o[7]);
                uhat[((size_t)(b0 + bb) * IC + i) * CH + c] = pk.q;
                #pragma unroll
                for (int j = 0; j < 8; ++j)
                    atomicAdd(&s0l[par][bb][8 * c + j], o[j]);
            }
        }
    }
    __syncthreads();

    // flush block partial to global (s0g zeroed by memset before launch)
    if (t < ROWH) {
        for (int bb = 0; bb < BC; ++bb)
            atomicAdd(&s0g[(size_t)(b0 + bb) * ROWH + t],
                      s0l[0][bb][t] + s0l[1][bb][t]);
    }
}

// ---------------------------------------------------------------------------
// K1b: v0 = squash(0.1 * s0). grid = 256 (b), 192 threads (t<160 active).
// t = (o<<4)|d; norm over the aligned 16-lane d-group via shfl_xor.
// ---------------------------------------------------------------------------
__global__ __launch_bounds__(192) void squash0_kernel(
    const float* __restrict__ s0g, float* __restrict__ v0g)
{
    const int b = blockIdx.x, t = threadIdx.x;
    if (t < ROWH) {
        float S = 0.1f * s0g[(size_t)b * ROWH + t];
        float n2 = S * S;
        n2 += __shfl_xor(n2, 1);
        n2 += __shfl_xor(n2, 2);
        n2 += __shfl_xor(n2, 4);
        n2 += __shfl_xor(n2, 8);
        float sc = (n2 / (1.0f + n2)) * rsqrtf(n2 + 1e-8f);
        v0g[(size_t)b * ROWH + t] = S * sc;
    }
}

// ---------------------------------------------------------------------------
// K2: routing passes P1, P2 only. One block per b, 1024 threads = 16 waves.
// Lane = ii*16 + os (ii: which of 4 i's this step; os: o-slot, 10 active).
// Each lane holds the full 32B u_hat row for its (i,o): in-lane 16-d dot,
// ONE exp per (i,o), Z via 4 shfls in the aligned 16-group, s[16] in regs.
// Wave wv covers i in [wv*72, wv*72+72), 4 per step, 18 steps, depth-2 pipe.
// ---------------------------------------------------------------------------
__global__ __launch_bounds__(1024) void routing2_kernel(
    const uint4* __restrict__ uhat, const float* __restrict__ v0g,
    float* __restrict__ out)
{
    const int b  = blockIdx.x;
    const int t  = threadIdx.x;
    const int wv = t >> 6;
    const int ln = t & 63;
    const int ii = ln >> 4;
    const int os = ln & 15;
    const bool act = (os < OC);
    const int o  = act ? os : (OC - 1);

    __shared__ float sred[16][164];   // +4 pad: 2-way max conflict on reduce
    __shared__ float vl[ROWH];

    const char* base = (const char*)uhat + (size_t)b * IC * 320 + o * 32;

    float v[16];
    {
        const float4* vp = (const float4*)(v0g + (size_t)b * ROWH + o * 16);
        float4 q0 = vp[0], q1 = vp[1], q2 = vp[2], q3 = vp[3];
        v[0]=q0.x; v[1]=q0.y; v[2]=q0.z; v[3]=q0.w;
        v[4]=q1.x; v[5]=q1.y; v[6]=q1.z; v[7]=q1.w;
        v[8]=q2.x; v[9]=q2.y; v[10]=q2.z; v[11]=q2.w;
        v[12]=q3.x; v[13]=q3.y; v[14]=q3.z; v[15]=q3.w;
    }

    const int ibase = wv * 72 + ii;

    for (int p = 1; p <= 2; ++p) {
        float s[16];
        #pragma unroll
        for (int j = 0; j < 16; ++j) s[j] = 0.f;

        uint4 A0 = *(const uint4*)(base + (size_t)ibase * 320);
        uint4 A1 = *(const uint4*)(base + (size_t)ibase * 320 + 16);
        uint4 B0 = *(const uint4*)(base + (size_t)(ibase + 4) * 320);
        uint4 B1 = *(const uint4*)(base + (size_t)(ibase + 4) * 320 + 16);

        #pragma unroll 2
        for (int it = 0; it < 18; ++it) {
            uint4 N0 = B0, N1 = B1;
            if (it + 2 < 18) {
                const char* np = base + (size_t)(ibase + (it + 2) * 4) * 320;
                N0 = *(const uint4*)np;
                N1 = *(const uint4*)(np + 16);
            }

            float r[16];
            const __half2* hp0 = (const __half2*)&A0;
            const __half2* hp1 = (const __half2*)&A1;
            #pragma unroll
            for (int q = 0; q < 4; ++q) {
                float2 f = __half22float2(hp0[q]);
                float2 g = __half22float2(hp1[q]);
                r[2 * q]     = f.x; r[2 * q + 1] = f.y;
                r[8 + 2 * q] = g.x; r[9 + 2 * q] = g.y;
            }

            float a = 0.f;
            #pragma unroll
            for (int j = 0; j < 16; ++j) a += r[j] * v[j];

            float e = act ? __expf(a) : 0.f;
            float Z = e;
            Z += __shfl_xor(Z, 1);
            Z += __shfl_xor(Z, 2);
            Z += __shfl_xor(Z, 4);
            Z += __shfl_xor(Z, 8);
            float cf = __fdividef(e, Z);

            #pragma unroll
            for (int j = 0; j < 16; ++j) s[j] += cf * r[j];

            A0 = B0; A1 = B1; B0 = N0; B1 = N1;
        }

        // reduce over the 4 ii (lanes xor 16, 32 share the same os)
        #pragma unroll
        for (int j = 0; j < 16; ++j) {
            s[j] += __shfl_xor(s[j], 16);
            s[j] += __shfl_xor(s[j], 32);
        }
        if (ln < 16 && act) {   // ii==0, os<10: holds wave-total for o=os
            float4* dst = (float4*)&sred[wv][os * 16];
            dst[0] = make_float4(s[0],  s[1],  s[2],  s[3]);
            dst[1] = make_float4(s[4],  s[5],  s[6],  s[7]);
            dst[2] = make_float4(s[8],  s[9],  s[10], s[11]);
            dst[3] = make_float4(s[12], s[13], s[14], s[15]);
        }
        __syncthreads();

        if (t < ROWH) {
            float S = 0.f;
            #pragma unroll
            for (int w2 = 0; w2 < 16; ++w2) S += sred[w2][t];
            float n2 = S * S;
            n2 += __shfl_xor(n2, 1);
            n2 += __shfl_xor(n2, 2);
            n2 += __shfl_xor(n2, 4);
            n2 += __shfl_xor(n2, 8);
            float sc = (n2 / (1.0f + n2)) * rsqrtf(n2 + 1e-8f);
            vl[t] = S * sc;
        }
        __syncthreads();

        if (p == 1) {   // v <- v0 + v1 for pass 2's logits
            const float4* vp = (const float4*)&vl[o * 16];
            float4 q0 = vp[0], q1 = vp[1], q2 = vp[2], q3 = vp[3];
            v[0]+=q0.x; v[1]+=q0.y; v[2]+=q0.z; v[3]+=q0.w;
            v[4]+=q1.x; v[5]+=q1.y; v[6]+=q1.z; v[7]+=q1.w;
            v[8]+=q2.x; v[9]+=q2.y; v[10]+=q2.z; v[11]+=q2.w;
            v[12]+=q3.x; v[13]+=q3.y; v[14]+=q3.z; v[15]+=q3.w;
            __syncthreads();   // protect sred before p=2 rewrites it
        }
    }

    if (t < 2 * CH) {
        ((float4*)out)[(size_t)b * 2 * CH + t] = ((const float4*)vl)[t];
    }
}

// ---------------------------------------------------------------------------
extern "C" void kernel_launch(void* const* d_in, const int* in_sizes, int n_in,
                              void* d_out, int out_size, void* d_ws, size_t ws_size,
                              hipStream_t stream)
{
    const float* u = (const float*)d_in[0];
    const float* W = (const float*)d_in[1];

    const size_t UHAT_BYTES = (size_t)B_SZ * IC * CH * 16;   // 94,371,840
    char* ws = (char*)d_ws;
    uint4* uhat = (uint4*)ws;
    float* s0g  = (float*)(ws + UHAT_BYTES);                 // 256*160 f32
    float* v0g  = (float*)(ws + UHAT_BYTES + (size_t)B_SZ * ROWH * 4);

    hipMemsetAsync(s0g, 0, (size_t)B_SZ * ROWH * 4, stream);
    uhat_s0_kernel<<<(IC / ICH) * (B_SZ / BC), 256, 0, stream>>>(u, W, uhat, s0g);
    squash0_kernel<<<B_SZ, 192, 0, stream>>>(s0g, v0g);
    routing2_kernel<<<B_SZ, 1024, 0, stream>>>(uhat, v0g, (float*)d_out);
}

// Round 6
// 144.501 us; speedup vs baseline: 2.8393x; 2.8393x over previous
//
#include <hip/hip_runtime.h>
#include <hip/hip_fp16.h>

#define B_SZ  256
#define IC    1152
#define ID    8
#define OC    10
#define ODIM  16
#define ROWH  160      // halves per (b,i) row of u_hat
#define CH    20       // uint4 (8-half) chunks per row

// ---------------------------------------------------------------------------
// K1: u_hat[b][i][od] = sum_k W[i][od][k] * u[b][i][k], stored fp16.
// grid = 1152 (one block per i), 256 threads (thread = b). All lanes active.
// W[i] (5 KB) staged in LDS, consumed as uniform-broadcast ds_read_b128
// (no per-lane register cache -> no spill fragility, cf. R5 post-mortem).
// Stores: 20 contiguous uint4 per lane (320 B row per (b,i)).
// ---------------------------------------------------------------------------
__global__ __launch_bounds__(256) void uhat_b_kernel(
    const float* __restrict__ u, const float* __restrict__ W,
    uint4* __restrict__ uhat)
{
    const int i = blockIdx.x;
    const int b = threadIdx.x;

    __shared__ float4 Wl[ROWH * 2];   // 160 od x 8 k = 1280 f32 = 320 float4

    const float4* wsrc = (const float4*)(W + (size_t)i * ROWH * ID);
    for (int idx = b; idx < ROWH * 2; idx += 256) Wl[idx] = wsrc[idx];

    const float4* up = (const float4*)(u + ((size_t)b * IC + i) * ID);
    float4 u0 = up[0], u1 = up[1];
    __syncthreads();

    uint4* dst = uhat + ((size_t)b * IC + i) * CH;
    #pragma unroll 4
    for (int c4 = 0; c4 < CH; ++c4) {
        float o[8];
        #pragma unroll
        for (int j = 0; j < 8; ++j) {
            float4 wa = Wl[(c4 * 8 + j) * 2];
            float4 wb = Wl[(c4 * 8 + j) * 2 + 1];
            o[j] = wa.x * u0.x + wa.y * u0.y + wa.z * u0.z + wa.w * u0.w
                 + wb.x * u1.x + wb.y * u1.y + wb.z * u1.z + wb.w * u1.w;
        }
        union { __half2 h2[4]; uint4 q; } pk;
        pk.h2[0] = __floats2half2_rn(o[0], o[1]);
        pk.h2[1] = __floats2half2_rn(o[2], o[3]);
        pk.h2[2] = __floats2half2_rn(o[4], o[5]);
        pk.h2[3] = __floats2half2_rn(o[6], o[7]);
        dst[c4] = pk.q;
    }
}

// ---------------------------------------------------------------------------
// K2: all 3 routing passes. One block per b, 1024 threads = 16 waves.
// Lane = ii*16 + os (ii: which of 4 i's this step; os: o-slot, 10 active).
// Each lane holds the full 32B u_hat row for its (i,o): in-lane 16-d dot,
// ONE exp per (i,o) (passes 1,2; pass 0 is exp-free uniform c=0.1),
// Z via 4 shfls in the aligned 16-group, s[16] in regs, depth-2 load pipe.
// b-logits never stored: b_p = u_hat . (v0+..+v_{p-1}) (running v regs).
// ---------------------------------------------------------------------------
__global__ __launch_bounds__(1024) void routing3_kernel(
    const uint4* __restrict__ uhat, float* __restrict__ out)
{
    const int b  = blockIdx.x;
    const int t  = threadIdx.x;
    const int wv = t >> 6;
    const int ln = t & 63;
    const int ii = ln >> 4;
    const int os = ln & 15;
    const bool act = (os < OC);
    const int o  = act ? os : (OC - 1);

    __shared__ float sred[16][164];   // +4 pad
    __shared__ float vl[ROWH];

    const char* base = (const char*)uhat + (size_t)b * IC * 320 + o * 32;

    float v[16];
    #pragma unroll
    for (int j = 0; j < 16; ++j) v[j] = 0.f;

    const int ibase = wv * 72 + ii;

    for (int p = 0; p < 3; ++p) {
        float s[16];
        #pragma unroll
        for (int j = 0; j < 16; ++j) s[j] = 0.f;

        uint4 A0 = *(const uint4*)(base + (size_t)ibase * 320);
        uint4 A1 = *(const uint4*)(base + (size_t)ibase * 320 + 16);
        uint4 B0 = *(const uint4*)(base + (size_t)(ibase + 4) * 320);
        uint4 B1 = *(const uint4*)(base + (size_t)(ibase + 4) * 320 + 16);

        #pragma unroll 2
        for (int it = 0; it < 18; ++it) {
            uint4 N0 = B0, N1 = B1;
            if (it + 2 < 18) {
                const char* np = base + (size_t)(ibase + (it + 2) * 4) * 320;
                N0 = *(const uint4*)np;
                N1 = *(const uint4*)(np + 16);
            }

            float r[16];
            const __half2* hp0 = (const __half2*)&A0;
            const __half2* hp1 = (const __half2*)&A1;
            #pragma unroll
            for (int q = 0; q < 4; ++q) {
                float2 f = __half22float2(hp0[q]);
                float2 g = __half22float2(hp1[q]);
                r[2 * q]     = f.x; r[2 * q + 1] = f.y;
                r[8 + 2 * q] = g.x; r[9 + 2 * q] = g.y;
            }

            if (p == 0) {
                #pragma unroll
                for (int j = 0; j < 16; ++j) s[j] += r[j];   // c uniform; 0.1 later
            } else {
                float a = 0.f;
                #pragma unroll
                for (int j = 0; j < 16; ++j) a += r[j] * v[j];

                float e = act ? __expf(a) : 0.f;
                float Z = e;
                Z += __shfl_xor(Z, 1);
                Z += __shfl_xor(Z, 2);
                Z += __shfl_xor(Z, 4);
                Z += __shfl_xor(Z, 8);
                float cf = __fdividef(e, Z);

                #pragma unroll
                for (int j = 0; j < 16; ++j) s[j] += cf * r[j];
            }

            A0 = B0; A1 = B1; B0 = N0; B1 = N1;
        }

        // reduce over the 4 ii (lanes xor 16, 32 share the same os)
        #pragma unroll
        for (int j = 0; j < 16; ++j) {
            s[j] += __shfl_xor(s[j], 16);
            s[j] += __shfl_xor(s[j], 32);
        }
        if (ln < 16 && act) {   // ii==0, os<10: wave-total for o=os
            float4* dst = (float4*)&sred[wv][os * 16];
            dst[0] = make_float4(s[0],  s[1],  s[2],  s[3]);
            dst[1] = make_float4(s[4],  s[5],  s[6],  s[7]);
            dst[2] = make_float4(s[8],  s[9],  s[10], s[11]);
            dst[3] = make_float4(s[12], s[13], s[14], s[15]);
        }
        __syncthreads();

        if (t < ROWH) {
            float S = 0.f;
            #pragma unroll
            for (int w2 = 0; w2 < 16; ++w2) S += sred[w2][t];
            if (p == 0) S *= 0.1f;
            float n2 = S * S;
            n2 += __shfl_xor(n2, 1);
            n2 += __shfl_xor(n2, 2);
            n2 += __shfl_xor(n2, 4);
            n2 += __shfl_xor(n2, 8);
            float sc = (n2 / (1.0f + n2)) * rsqrtf(n2 + 1e-8f);
            vl[t] = S * sc;
        }
        __syncthreads();

        if (p < 2) {   // v <- v0 (p0) ; v <- v0+v1 (p1)
            const float4* vp = (const float4*)&vl[o * 16];
            float4 q0 = vp[0], q1 = vp[1], q2 = vp[2], q3 = vp[3];
            if (p == 0) {
                v[0]=q0.x; v[1]=q0.y; v[2]=q0.z; v[3]=q0.w;
                v[4]=q1.x; v[5]=q1.y; v[6]=q1.z; v[7]=q1.w;
                v[8]=q2.x; v[9]=q2.y; v[10]=q2.z; v[11]=q2.w;
                v[12]=q3.x; v[13]=q3.y; v[14]=q3.z; v[15]=q3.w;
            } else {
                v[0]+=q0.x; v[1]+=q0.y; v[2]+=q0.z; v[3]+=q0.w;
                v[4]+=q1.x; v[5]+=q1.y; v[6]+=q1.z; v[7]+=q1.w;
                v[8]+=q2.x; v[9]+=q2.y; v[10]+=q2.z; v[11]+=q2.w;
                v[12]+=q3.x; v[13]+=q3.y; v[14]+=q3.z; v[15]+=q3.w;
            }
            __syncthreads();   // protect sred before next pass rewrites it
        }
    }

    if (t < 2 * CH) {
        ((float4*)out)[(size_t)b * 2 * CH + t] = ((const float4*)vl)[t];
    }
}

// ---------------------------------------------------------------------------
extern "C" void kernel_launch(void* const* d_in, const int* in_sizes, int n_in,
                              void* d_out, int out_size, void* d_ws, size_t ws_size,
                              hipStream_t stream)
{
    const float* u = (const float*)d_in[0];
    const float* W = (const float*)d_in[1];

    uint4* uhat = (uint4*)d_ws;   // 256*1152*320 B = 94.4 MB

    uhat_b_kernel<<<IC, 256, 0, stream>>>(u, W, uhat);
    routing3_kernel<<<B_SZ, 1024, 0, stream>>>(uhat, (float*)d_out);
}